// Round 1
// baseline (391.090 us; speedup 1.0000x reference)
//
#include <hip/hip_runtime.h>
#include <stdint.h>

typedef __bf16 bf16x8 __attribute__((ext_vector_type(8)));
typedef float  f32x4  __attribute__((ext_vector_type(4)));

#define DEV static __device__ __forceinline__

DEV unsigned short f2bf(float x) {
    union { float f; unsigned int u; } v; v.f = x;
    unsigned int r = v.u + 0x7FFFu + ((v.u >> 16) & 1u);
    return (unsigned short)(r >> 16);
}

DEV void gl_lds16(const void* g, void* l) {
    __builtin_amdgcn_global_load_lds(
        (__attribute__((address_space(1))) void*)(g),
        (__attribute__((address_space(3))) void*)(l), 16, 0, 0);
}

DEV f32x4 zero4() { f32x4 z; z[0]=0.f; z[1]=0.f; z[2]=0.f; z[3]=0.f; return z; }

// ---------------- fused prep: fp32->bf16 convert + two weight transposes ----------------
__global__ void k_prep(const float* __restrict__ hs, unsigned short* __restrict__ hs_bf,
                       const float* __restrict__ wqkv, unsigned short* __restrict__ wqkvT,
                       const float* __restrict__ wproj, unsigned short* __restrict__ wprojT) {
    __shared__ float tile[32][33];
    const int bid = blockIdx.x, t = threadIdx.x;
    if (bid < 2048) {
        #pragma unroll
        for (int j = 0; j < 4; j++) {
            int i = bid*4096 + j*1024 + t*4;
            float4 f = *(const float4*)(hs + i);
            ushort4 o;
            o.x = f2bf(f.x); o.y = f2bf(f.y); o.z = f2bf(f.z); o.w = f2bf(f.w);
            *(ushort4*)(hs_bf + i) = o;
        }
        return;
    }
    const float* in; unsigned short* out; int K, N, n0, k0;
    if (bid < 14336) {
        int ti = bid - 2048;           // wqkv: N=6144, K=2048
        in = wqkv; out = wqkvT; K = 2048; N = 6144;
        n0 = (ti % 192) * 32; k0 = (ti / 192) * 32;
    } else {
        int ti = bid - 14336;          // wproj: N=2048, K=2048
        in = wproj; out = wprojT; K = 2048; N = 2048;
        n0 = (ti % 64) * 32; k0 = (ti / 64) * 32;
    }
    const int tx = t & 31, ty = t >> 5;
    #pragma unroll
    for (int i = 0; i < 4; i++)
        tile[ty + i*8][tx] = in[(size_t)(k0 + ty + i*8) * N + n0 + tx];
    __syncthreads();
    #pragma unroll
    for (int i = 0; i < 4; i++)
        out[(size_t)(n0 + ty + i*8) * K + k0 + tx] = f2bf(tile[tx][ty + i*8]);
}

// ---------------- 128x256 bf16 GEMM, 3-buffer pipelined (counted vmcnt), 8 waves ----------------
// T3/T4: per K-tile two 16-MFMA phases; 6 gl_lds per tile issued inside phases; boundary wait
// is vmcnt(6) (keeps next tile's 6 loads in flight, guarantees current tile landed). Raw
// s_barrier (NOT __syncthreads -> would emit vmcnt(0) drain). T5: setprio around MFMA cluster.
// 3 K-tile LDS buffers (A 3x16KB + B 3x32KB = 144KB dynamic), 1 block/CU, 2 waves/SIMD.
// MODE 0: qkv epilogue (bf16 q/k scaled + per-head-transposed v). MODE 1: proj (fp32 + bias).
template<int MODE>
__launch_bounds__(512, 2)
__global__ void k_gemm_pipe(const unsigned short* __restrict__ A,
                            const unsigned short* __restrict__ BT,
                            const float* __restrict__ bias,
                            unsigned short* __restrict__ q_buf,
                            unsigned short* __restrict__ k_buf,
                            unsigned short* __restrict__ vt_buf,
                            float* __restrict__ outp) {
    constexpr int K = 2048, KT = 32;
    extern __shared__ char smem[];
    uint4* As = (uint4*)smem;                 // 3 buffers x 1024 uint4 (128 rows x 64 k)
    uint4* Bs = (uint4*)(smem + 49152);       // 3 buffers x 2048 uint4 (256 rows x 64 k)

    const int t = threadIdx.x;
    const int wid = t >> 6, lane = t & 63, quad = lane >> 4, l15 = lane & 15;
    const int wm = wid & 1, wn = wid >> 1;
    const int bm = blockIdx.x, bn = blockIdx.y;

    f32x4 acc[4][4];
    #pragma unroll
    for (int i = 0; i < 4; i++)
        #pragma unroll
        for (int j = 0; j < 4; j++) acc[i][j] = zero4();

    // staging precompute: LDS chunk s = j*512 + t holds global chunk (s&7)^(r&7) of row r=s>>3
    int arow[2], acol[2];
    #pragma unroll
    for (int j = 0; j < 2; j++) {
        int s = j*512 + t, r = s >> 3;
        arow[j] = r; acol[j] = ((s & 7) ^ (r & 7)) * 8;
    }
    int brow[4], bcol[4];
    #pragma unroll
    for (int j = 0; j < 4; j++) {
        int s = j*512 + t, r = s >> 3;
        brow[j] = r; bcol[j] = ((s & 7) ^ (r & 7)) * 8;
    }
    const unsigned short* Abase = A  + (size_t)(bm*128) * K;
    const unsigned short* Bbase = BT + (size_t)(bn*256) * K;
    const int dstw = wid << 6;  // wave-uniform LDS dest base component (HW adds lane*16)

    #define ST_A(buf, k0, j) gl_lds16(Abase + (size_t)arow[j]*K + (k0) + acol[j], As + (buf)*1024 + (j)*512 + dstw)
    #define ST_B(buf, k0, j) gl_lds16(Bbase + (size_t)brow[j]*K + (k0) + bcol[j], Bs + (buf)*2048 + (j)*512 + dstw)

    // prologue: stage tiles 0,1 fully; drain once (one-time cost)
    ST_A(0, 0, 0);  ST_A(0, 0, 1);
    ST_B(0, 0, 0);  ST_B(0, 0, 1);  ST_B(0, 0, 2);  ST_B(0, 0, 3);
    ST_A(1, 64, 0); ST_A(1, 64, 1);
    ST_B(1, 64, 0); ST_B(1, 64, 1); ST_B(1, 64, 2); ST_B(1, 64, 3);
    asm volatile("s_waitcnt vmcnt(0)" ::: "memory");
    __builtin_amdgcn_s_barrier();
    __builtin_amdgcn_sched_barrier(0);   // pin: no ds_read may hoist above readiness point

    int rb = 0, wb = 2;
    #pragma unroll 1
    for (int tk = 0; tk < KT; ++tk) {
        const uint4* Ar = As + rb*1024;
        const uint4* Br = Bs + rb*2048;
        const int k2 = (tk + 2) * 64;
        const bool st = (tk + 2 < KT);
        #pragma unroll
        for (int ks = 0; ks < 2; ++ks) {
            bf16x8 af[4], bv[4];
            #pragma unroll
            for (int mt = 0; mt < 4; mt++) {
                int row = wm*64 + mt*16 + l15;
                int g = (ks*4 + quad) ^ (row & 7);
                af[mt] = __builtin_bit_cast(bf16x8, Ar[row*8 + g]);
            }
            #pragma unroll
            for (int nt = 0; nt < 4; nt++) {
                int row = wn*64 + nt*16 + l15;
                int g = (ks*4 + quad) ^ (row & 7);
                bv[nt] = __builtin_bit_cast(bf16x8, Br[row*8 + g]);
            }
            if (st) {
                if (ks == 0) { ST_A(wb, k2, 0); ST_A(wb, k2, 1); ST_B(wb, k2, 0); }
                else         { ST_B(wb, k2, 1); ST_B(wb, k2, 2); ST_B(wb, k2, 3); }
            }
            __builtin_amdgcn_s_barrier();
            __builtin_amdgcn_s_setprio(1);
            #pragma unroll
            for (int mt = 0; mt < 4; mt++)
                #pragma unroll
                for (int nt = 0; nt < 4; nt++)
                    acc[mt][nt] = __builtin_amdgcn_mfma_f32_16x16x32_bf16(
                        af[mt], bv[nt], acc[mt][nt], 0, 0, 0);
            __builtin_amdgcn_s_setprio(0);
            if (ks == 1) {
                // boundary wait: tile tk+1's 6 loads are the oldest outstanding; tile tk+2's
                // 6 (just issued) may stay in flight -> counted vmcnt(6), never a drain.
                if (st)                asm volatile("s_waitcnt vmcnt(6)" ::: "memory");
                else if (tk + 1 < KT)  asm volatile("s_waitcnt vmcnt(0)" ::: "memory");
            }
            __builtin_amdgcn_s_barrier();
            if (ks == 1) __builtin_amdgcn_sched_barrier(0);  // next tile's reads stay below
        }
        rb = (rb == 2) ? 0 : rb + 1;
        wb = (wb == 2) ? 0 : wb + 1;
    }
    #undef ST_A
    #undef ST_B

    if (MODE == 0) {
        const int nglob = bn*256 + wn*64;
        const int seg = bn >> 3;                 // 0=q, 1=k, 2=v (8 bn-tiles per 2048 segment)
        const int cnb = nglob & 2047;
        if (seg < 2) {
            unsigned short* dst = (seg == 0) ? q_buf : k_buf;
            const float scl = (seg == 0) ? 0.08838834764831845f : 1.0f;  // 1/sqrt(128) in Q
            #pragma unroll
            for (int nt = 0; nt < 4; nt++) {
                int cn = cnb + nt*16 + l15;
                float bvv = bias[nglob + nt*16 + l15];
                #pragma unroll
                for (int mt = 0; mt < 4; mt++) {
                    int tt = bm*128 + wm*64 + mt*16 + quad*4;
                    #pragma unroll
                    for (int r = 0; r < 4; r++)
                        dst[(size_t)(tt + r) * 2048 + cn] = f2bf((acc[mt][nt][r] + bvv) * scl);
                }
            }
        } else {
            // V transposed per head: vt[(b*16+h)*128*1024 + d*1024 + s]
            #pragma unroll
            for (int nt = 0; nt < 4; nt++) {
                int cn = cnb + nt*16 + l15;
                int h = cn >> 7, d = cn & 127;
                float bvv = bias[nglob + nt*16 + l15];
                #pragma unroll
                for (int mt = 0; mt < 4; mt++) {
                    int tt = bm*128 + wm*64 + mt*16 + quad*4;
                    int b = tt >> 10, s = tt & 1023;
                    ushort4 pk;
                    pk.x = f2bf(acc[mt][nt][0] + bvv);
                    pk.y = f2bf(acc[mt][nt][1] + bvv);
                    pk.z = f2bf(acc[mt][nt][2] + bvv);
                    pk.w = f2bf(acc[mt][nt][3] + bvv);
                    *(ushort4*)(vt_buf + ((size_t)((b*16 + h)*128 + d) * 1024 + s)) = pk;
                }
            }
        }
    } else {
        #pragma unroll
        for (int nt = 0; nt < 4; nt++) {
            int n = bn*256 + wn*64 + nt*16 + l15;
            float bvv = bias[n];
            #pragma unroll
            for (int mt = 0; mt < 4; mt++) {
                int m = bm*128 + wm*64 + mt*16 + quad*4;
                #pragma unroll
                for (int r = 0; r < 4; r++)
                    outp[(size_t)(m + r) * 2048 + n] = acc[mt][nt][r] + bvv;
            }
        }
    }
}

// ---------------- flash attention (causal), static XCD-affine grid ----------------
// grid dim3(64,8): x=bh, y -> qt. bid%8 = bh%8 keeps all qt-items of one (b,h) on one XCD.
// qt remap y -> (y<4 ? y : 11-y): under round-robin dispatch CU c gets blocks (c, c+256),
// i.e. qt pairs (0,7)(1,6)(2,5)(3,4) -> per-CU iter count constant 18 (was 12..24, 33% tail).
// m=0 softmax (scores O(0.02)): exp stable without max-subtraction -> linear accumulation.
__launch_bounds__(256, 2)
__global__ void k_attn(const unsigned short* __restrict__ q_buf,
                       const unsigned short* __restrict__ k_buf,
                       const unsigned short* __restrict__ vt_buf,
                       unsigned short* __restrict__ ctx_buf) {
    __shared__ __align__(16) uint4 Ks[64*16];             // 64 keys x 128 d, swz ^(r&15)
    __shared__ __align__(16) uint4 Vs[128*8];             // 128 d x 64 keys, swz ^(r&7)
    __shared__ __align__(16) unsigned short Pl[4][32*64]; // per-wave P (32 rows), swz ^(row&7)

    const int t = threadIdx.x;
    const int wave = t >> 6, lane = t & 63, quad = lane >> 4, l15 = lane & 15;
    const int bh = blockIdx.x;
    const int yq = blockIdx.y;
    const int qt = (yq < 4) ? yq : (11 - yq);
    const int b = bh >> 4, h = bh & 15;

    bf16x8 qf[2][4];
    #pragma unroll
    for (int rt = 0; rt < 2; rt++) {
        const size_t qoff = (size_t)(b*1024 + qt*128 + wave*32 + rt*16 + l15) * 2048 + h*128;
        #pragma unroll
        for (int ks = 0; ks < 4; ks++)
            qf[rt][ks] = __builtin_bit_cast(bf16x8, *(const uint4*)(q_buf + qoff + ks*32 + quad*8));
    }

    f32x4 ctx[2][8];
    #pragma unroll
    for (int rt = 0; rt < 2; rt++)
        #pragma unroll
        for (int i = 0; i < 8; i++) ctx[rt][i] = zero4();
    float l_run[2][4];
    #pragma unroll
    for (int rt = 0; rt < 2; rt++)
        #pragma unroll
        for (int r = 0; r < 4; r++) l_run[rt][r] = 0.f;

    const size_t kbase = (size_t)b * 1024 * 2048 + h*128;
    const size_t vbase = (size_t)(b*16 + h) * 131072;
    const int row0 = qt*128 + wave*32;

    const int kiters = 2*qt + 2;
    for (int kt = 0; kt < kiters; kt++) {
        __syncthreads();
        #pragma unroll
        for (int p = 0; p < 4; p++) {
            int c = p*4 + wave;
            {   // K tile
                int s = c*64 + lane;
                int r = s >> 4;
                int g = (s & 15) ^ (r & 15);
                gl_lds16(k_buf + kbase + (size_t)(kt*64 + r) * 2048 + g*8, &Ks[c*64]);
            }
            {   // Vt tile
                int s = c*64 + lane;
                int r = s >> 3;
                int g = (lane & 7) ^ (r & 7);
                gl_lds16(vt_buf + vbase + (size_t)r * 1024 + kt*64 + g*8, &Vs[c*64]);
            }
        }
        __syncthreads();

        if (kt*64 > row0 + 31) continue;          // whole wave masked
        const bool needmask = (kt*64 + 63 > row0);

        // S = Q K^T, K-fragment shared across both row-tiles
        f32x4 sacc[2][4];
        #pragma unroll
        for (int rt = 0; rt < 2; rt++)
            #pragma unroll
            for (int nt = 0; nt < 4; nt++) sacc[rt][nt] = zero4();
        #pragma unroll
        for (int ks = 0; ks < 4; ks++)
            #pragma unroll
            for (int nt = 0; nt < 4; nt++) {
                int key = nt*16 + l15;
                int g = (ks*4 + quad) ^ (key & 15);
                bf16x8 kf = __builtin_bit_cast(bf16x8, Ks[key*16 + g]);
                sacc[0][nt] = __builtin_amdgcn_mfma_f32_16x16x32_bf16(qf[0][ks], kf, sacc[0][nt], 0, 0, 0);
                sacc[1][nt] = __builtin_amdgcn_mfma_f32_16x16x32_bf16(qf[1][ks], kf, sacc[1][nt], 0, 0, 0);
            }

        #pragma unroll
        for (int rt = 0; rt < 2; rt++) {
            float pv[4][4];
            if (needmask) {
                #pragma unroll
                for (int nt = 0; nt < 4; nt++)
                    #pragma unroll
                    for (int r = 0; r < 4; r++) {
                        bool masked = (kt*64 + nt*16 + l15 > row0 + rt*16 + quad*4 + r);
                        pv[nt][r] = masked ? 0.f : __expf(sacc[rt][nt][r]);
                    }
            } else {
                #pragma unroll
                for (int nt = 0; nt < 4; nt++)
                    #pragma unroll
                    for (int r = 0; r < 4; r++)
                        pv[nt][r] = __expf(sacc[rt][nt][r]);
            }
            #pragma unroll
            for (int r = 0; r < 4; r++)
                l_run[rt][r] += (pv[0][r] + pv[1][r]) + (pv[2][r] + pv[3][r]);

            #pragma unroll
            for (int nt = 0; nt < 4; nt++)
                #pragma unroll
                for (int r = 0; r < 4; r++) {
                    int row = rt*16 + quad*4 + r;
                    int col = nt*16 + l15;
                    int gc = (col >> 3) ^ (row & 7);
                    Pl[wave][row*64 + gc*8 + (col & 7)] = f2bf(pv[nt][r]);
                }
        }
        __asm__ volatile("s_waitcnt lgkmcnt(0)" ::: "memory");

        // ctx += P V, V-fragment shared across both row-tiles
        #pragma unroll
        for (int ks = 0; ks < 2; ks++) {
            bf16x8 pa[2];
            #pragma unroll
            for (int rt = 0; rt < 2; rt++) {
                int row = rt*16 + l15;
                int gp = (ks*4 + quad) ^ (row & 7);
                pa[rt] = __builtin_bit_cast(bf16x8, *(const uint4*)&Pl[wave][row*64 + gp*8]);
            }
            #pragma unroll
            for (int dt = 0; dt < 8; dt++) {
                int drow = dt*16 + l15;
                int gv = (ks*4 + quad) ^ (drow & 7);
                bf16x8 vf = __builtin_bit_cast(bf16x8, Vs[drow*8 + gv]);
                ctx[0][dt] = __builtin_amdgcn_mfma_f32_16x16x32_bf16(pa[0], vf, ctx[0][dt], 0, 0, 0);
                ctx[1][dt] = __builtin_amdgcn_mfma_f32_16x16x32_bf16(pa[1], vf, ctx[1][dt], 0, 0, 0);
            }
        }
    }

    // finalize
    #pragma unroll
    for (int rt = 0; rt < 2; rt++) {
        float inv[4];
        #pragma unroll
        for (int r = 0; r < 4; r++) {
            float l = l_run[rt][r];
            l += __shfl_xor(l, 1);
            l += __shfl_xor(l, 2);
            l += __shfl_xor(l, 4);
            l += __shfl_xor(l, 8);
            inv[r] = 1.0f / l;
        }
        const int tt0 = b*1024 + qt*128 + wave*32 + rt*16 + quad*4;
        #pragma unroll
        for (int dt = 0; dt < 8; dt++)
            #pragma unroll
            for (int r = 0; r < 4; r++)
                ctx_buf[(size_t)(tt0 + r) * 2048 + h*128 + dt*16 + l15] = f2bf(ctx[rt][dt][r] * inv[r]);
    }
}

// ---------------- launch ----------------
extern "C" void kernel_launch(void* const* d_in, const int* in_sizes, int n_in,
                              void* d_out, int out_size, void* d_ws, size_t ws_size,
                              hipStream_t stream) {
    const float* hs    = (const float*)d_in[0];
    const float* wqkv  = (const float*)d_in[1];
    const float* bqkv  = (const float*)d_in[2];
    const float* wproj = (const float*)d_in[3];
    const float* bproj = (const float*)d_in[4];

    char* ws = (char*)d_ws;
    unsigned short* hs_bf   = (unsigned short*)(ws);
    unsigned short* wqkvT   = (unsigned short*)(ws + 16777216ull);
    unsigned short* wprojT  = (unsigned short*)(ws + 41943040ull);
    unsigned short* q_buf   = (unsigned short*)(ws + 50331648ull);
    unsigned short* k_buf   = (unsigned short*)(ws + 67108864ull);
    unsigned short* vt_buf  = (unsigned short*)(ws + 83886080ull);
    unsigned short* ctx_buf = (unsigned short*)(ws + 100663296ull);

    static bool attr_set = false;
    if (!attr_set) {
        hipFuncSetAttribute((const void*)k_gemm_pipe<0>,
                            hipFuncAttributeMaxDynamicSharedMemorySize, 147456);
        hipFuncSetAttribute((const void*)k_gemm_pipe<1>,
                            hipFuncAttributeMaxDynamicSharedMemorySize, 147456);
        attr_set = true;
    }

    k_prep<<<18432, 256, 0, stream>>>(hs, hs_bf, wqkv, wqkvT, wproj, wprojT);
    k_gemm_pipe<0><<<dim3(32, 24), 512, 147456, stream>>>(hs_bf, wqkvT, bqkv,
                                                          q_buf, k_buf, vt_buf, nullptr);
    k_attn<<<dim3(64, 8), 256, 0, stream>>>(q_buf, k_buf, vt_buf, ctx_buf);
    k_gemm_pipe<1><<<dim3(32, 8), 512, 147456, stream>>>(ctx_buf, wprojT, bproj,
                                                         nullptr, nullptr, nullptr, (float*)d_out);
}

// Round 3
// 373.622 us; speedup vs baseline: 1.0468x; 1.0468x over previous
//
#include <hip/hip_runtime.h>
#include <stdint.h>

typedef __bf16 bf16x8 __attribute__((ext_vector_type(8)));
typedef float  f32x4  __attribute__((ext_vector_type(4)));

#define DEV static __device__ __forceinline__

DEV unsigned short f2bf(float x) {
    union { float f; unsigned int u; } v; v.f = x;
    unsigned int r = v.u + 0x7FFFu + ((v.u >> 16) & 1u);
    return (unsigned short)(r >> 16);
}

DEV void gl_lds16(const void* g, void* l) {
    __builtin_amdgcn_global_load_lds(
        (__attribute__((address_space(1))) void*)(g),
        (__attribute__((address_space(3))) void*)(l), 16, 0, 0);
}

DEV f32x4 zero4() { f32x4 z; z[0]=0.f; z[1]=0.f; z[2]=0.f; z[3]=0.f; return z; }

// ---------------- fused prep: fp32->bf16 convert + two weight transposes ----------------
__global__ void k_prep(const float* __restrict__ hs, unsigned short* __restrict__ hs_bf,
                       const float* __restrict__ wqkv, unsigned short* __restrict__ wqkvT,
                       const float* __restrict__ wproj, unsigned short* __restrict__ wprojT) {
    __shared__ float tile[32][33];
    const int bid = blockIdx.x, t = threadIdx.x;
    if (bid < 2048) {
        #pragma unroll
        for (int j = 0; j < 4; j++) {
            int i = bid*4096 + j*1024 + t*4;
            float4 f = *(const float4*)(hs + i);
            ushort4 o;
            o.x = f2bf(f.x); o.y = f2bf(f.y); o.z = f2bf(f.z); o.w = f2bf(f.w);
            *(ushort4*)(hs_bf + i) = o;
        }
        return;
    }
    const float* in; unsigned short* out; int K, N, n0, k0;
    if (bid < 14336) {
        int ti = bid - 2048;           // wqkv: N=6144, K=2048
        in = wqkv; out = wqkvT; K = 2048; N = 6144;
        n0 = (ti % 192) * 32; k0 = (ti / 192) * 32;
    } else {
        int ti = bid - 14336;          // wproj: N=2048, K=2048
        in = wproj; out = wprojT; K = 2048; N = 2048;
        n0 = (ti % 64) * 32; k0 = (ti / 64) * 32;
    }
    const int tx = t & 31, ty = t >> 5;
    #pragma unroll
    for (int i = 0; i < 4; i++)
        tile[ty + i*8][tx] = in[(size_t)(k0 + ty + i*8) * N + n0 + tx];
    __syncthreads();
    #pragma unroll
    for (int i = 0; i < 4; i++)
        out[(size_t)(n0 + ty + i*8) * K + k0 + tx] = f2bf(tile[tx][ty + i*8]);
}

// ---------------- 128x128 bf16 GEMM (qkv epilogue) — proven 2-barrier structure ----------------
__launch_bounds__(256, 4)
__global__ void k_gemm_qkv(const unsigned short* __restrict__ A,
                           const unsigned short* __restrict__ BT,
                           const float* __restrict__ bias,
                           unsigned short* __restrict__ q_buf,
                           unsigned short* __restrict__ k_buf,
                           unsigned short* __restrict__ vt_buf,
                           int K) {
    __shared__ __align__(16) uint4 As[128*8];
    __shared__ __align__(16) uint4 Bs[128*8];

    const int t = threadIdx.x;
    const int wave = t >> 6, lane = t & 63, quad = lane >> 4, l15 = lane & 15;
    const int wm = wave & 1, wn = wave >> 1;
    const int bm = blockIdx.x, bn = blockIdx.y;

    f32x4 acc[4][4];
    #pragma unroll
    for (int i = 0; i < 4; i++)
        #pragma unroll
        for (int j = 0; j < 4; j++) acc[i][j] = zero4();

    int rS[4], gS[4];
    #pragma unroll
    for (int p = 0; p < 4; p++) {
        int c = p*4 + wave;
        int s = c*64 + lane;
        int r = s >> 3;
        rS[p] = r; gS[p] = (lane & 7) ^ (r & 7);
    }
    const unsigned short* Abase = A  + (size_t)(bm*128) * K;
    const unsigned short* Bbase = BT + (size_t)(bn*128) * K;

    const int kiters = K >> 6;
    for (int kk = 0; kk < kiters; kk++) {
        const int k0 = kk * 64;
        __syncthreads();
        #pragma unroll
        for (int p = 0; p < 4; p++) {
            int c = p*4 + wave;
            gl_lds16(Abase + (size_t)rS[p]*K + k0 + gS[p]*8, &As[c*64]);
            gl_lds16(Bbase + (size_t)rS[p]*K + k0 + gS[p]*8, &Bs[c*64]);
        }
        __syncthreads();
        #pragma unroll
        for (int ks = 0; ks < 2; ks++) {
            bf16x8 af[4], bfr[4];
            #pragma unroll
            for (int mt = 0; mt < 4; mt++) {
                int row = wm*64 + mt*16 + l15;
                int g = (ks*4 + quad) ^ (row & 7);
                af[mt] = __builtin_bit_cast(bf16x8, As[row*8 + g]);
            }
            #pragma unroll
            for (int nt = 0; nt < 4; nt++) {
                int row = wn*64 + nt*16 + l15;
                int g = (ks*4 + quad) ^ (row & 7);
                bfr[nt] = __builtin_bit_cast(bf16x8, Bs[row*8 + g]);
            }
            #pragma unroll
            for (int mt = 0; mt < 4; mt++)
                #pragma unroll
                for (int nt = 0; nt < 4; nt++)
                    acc[mt][nt] = __builtin_amdgcn_mfma_f32_16x16x32_bf16(
                        af[mt], bfr[nt], acc[mt][nt], 0, 0, 0);
        }
    }

    const int nglob = bn * 128;
    const int seg = nglob >> 11;                 // 0=q, 1=k, 2=v
    const int cn_base = (nglob & 2047) + wn*64;
    if (seg < 2) {
        unsigned short* dst = (seg == 0) ? q_buf : k_buf;
        const float scl = (seg == 0) ? 0.08838834764831845f : 1.0f;  // 1/sqrt(128) in Q
        #pragma unroll
        for (int nt = 0; nt < 4; nt++) {
            int cn = cn_base + nt*16 + l15;
            float bv = bias[nglob + wn*64 + nt*16 + l15];
            #pragma unroll
            for (int mt = 0; mt < 4; mt++) {
                int tt = bm*128 + wm*64 + mt*16 + quad*4;
                #pragma unroll
                for (int r = 0; r < 4; r++)
                    dst[(size_t)(tt + r) * 2048 + cn] = f2bf((acc[mt][nt][r] + bv) * scl);
            }
        }
    } else {
        // V transposed per head: vt[(b*16+h)*128*1024 + d*1024 + s]
        #pragma unroll
        for (int nt = 0; nt < 4; nt++) {
            int cn = cn_base + nt*16 + l15;
            int h = cn >> 7, d = cn & 127;
            float bv = bias[nglob + wn*64 + nt*16 + l15];
            #pragma unroll
            for (int mt = 0; mt < 4; mt++) {
                int tt = bm*128 + wm*64 + mt*16 + quad*4;
                int b = tt >> 10, s = tt & 1023;
                ushort4 pk;
                pk.x = f2bf(acc[mt][nt][0] + bv);
                pk.y = f2bf(acc[mt][nt][1] + bv);
                pk.z = f2bf(acc[mt][nt][2] + bv);
                pk.w = f2bf(acc[mt][nt][3] + bv);
                *(ushort4*)(vt_buf + ((size_t)((b*16 + h)*128 + d) * 1024 + s)) = pk;
            }
        }
    }
}

// ---------------- 64x128 bf16 GEMM (proj, fp32 out) — proven 2-barrier structure ----------------
__launch_bounds__(256, 4)
__global__ void k_gemm_proj(const unsigned short* __restrict__ A,
                            const unsigned short* __restrict__ BT,
                            const float* __restrict__ bias,
                            float* __restrict__ outp,
                            int N, int K) {
    __shared__ __align__(16) uint4 As[64*8];
    __shared__ __align__(16) uint4 Bs[128*8];

    const int t = threadIdx.x;
    const int wave = t >> 6, lane = t & 63, quad = lane >> 4, l15 = lane & 15;
    const int wm = wave & 1, wn = wave >> 1;
    const int bm = blockIdx.x, bn = blockIdx.y;

    f32x4 acc[2][4];
    #pragma unroll
    for (int i = 0; i < 2; i++)
        #pragma unroll
        for (int j = 0; j < 4; j++) acc[i][j] = zero4();

    int rS[4], gS[4];
    #pragma unroll
    for (int p = 0; p < 4; p++) {
        int c = p*4 + wave;
        int s = c*64 + lane;
        int r = s >> 3;
        rS[p] = r; gS[p] = (lane & 7) ^ (r & 7);
    }
    const unsigned short* Abase = A  + (size_t)(bm*64)  * K;
    const unsigned short* Bbase = BT + (size_t)(bn*128) * K;

    const int kiters = K >> 6;
    for (int kk = 0; kk < kiters; kk++) {
        const int k0 = kk * 64;
        __syncthreads();
        #pragma unroll
        for (int p = 0; p < 4; p++) {
            int c = p*4 + wave;
            if (p < 2)
                gl_lds16(Abase + (size_t)rS[p]*K + k0 + gS[p]*8, &As[c*64]);
            gl_lds16(Bbase + (size_t)rS[p]*K + k0 + gS[p]*8, &Bs[c*64]);
        }
        __syncthreads();
        #pragma unroll
        for (int ks = 0; ks < 2; ks++) {
            bf16x8 af[2], bfr[4];
            #pragma unroll
            for (int mt = 0; mt < 2; mt++) {
                int row = wm*32 + mt*16 + l15;
                int g = (ks*4 + quad) ^ (row & 7);
                af[mt] = __builtin_bit_cast(bf16x8, As[row*8 + g]);
            }
            #pragma unroll
            for (int nt = 0; nt < 4; nt++) {
                int row = wn*64 + nt*16 + l15;
                int g = (ks*4 + quad) ^ (row & 7);
                bfr[nt] = __builtin_bit_cast(bf16x8, Bs[row*8 + g]);
            }
            #pragma unroll
            for (int mt = 0; mt < 2; mt++)
                #pragma unroll
                for (int nt = 0; nt < 4; nt++)
                    acc[mt][nt] = __builtin_amdgcn_mfma_f32_16x16x32_bf16(
                        af[mt], bfr[nt], acc[mt][nt], 0, 0, 0);
        }
    }

    #pragma unroll
    for (int nt = 0; nt < 4; nt++) {
        int n = bn*128 + wn*64 + nt*16 + l15;
        float bv = bias[n];
        #pragma unroll
        for (int mt = 0; mt < 2; mt++) {
            int m = bm*64 + wm*32 + mt*16 + quad*4;
            #pragma unroll
            for (int r = 0; r < 4; r++)
                outp[(size_t)(m + r) * N + n] = acc[mt][nt][r] + bv;
        }
    }
}

// ---------------- flash attention (causal), double-buffered K/V pipeline ----------------
// grid dim3(64,8): x=bh, y -> qt; bid%8 = bh%8 keeps all qt of one (b,h) on one XCD (L2 reuse).
// qt remap y -> (y<4 ? y : 11-y): co-resident block pairs get balanced iteration counts.
// T14 pipeline: K/V tiles double-buffered in LDS; stage(t+1) ISSUED at top of iter t (8
// global_load_lds/thread), compute(t) runs on already-resident buffer, single end-of-iter
// __syncthreads (its vmcnt(0) drain is covered by ~1000cy of compute). 1 barrier/iter (was 2,
// with a serial ~600cy stage drain between them).
// m=0 softmax (scores O(0.02)): exp stable without max-subtraction -> linear accumulation.
__launch_bounds__(256, 2)
__global__ void k_attn(const unsigned short* __restrict__ q_buf,
                       const unsigned short* __restrict__ k_buf,
                       const unsigned short* __restrict__ vt_buf,
                       unsigned short* __restrict__ ctx_buf) {
    extern __shared__ char smem[];
    uint4* Ks = (uint4*)smem;                              // [2][64*16]  64 keys x 128 d, swz ^(r&15)
    uint4* Vs = (uint4*)(smem + 32768);                    // [2][128*8] 128 d x 64 keys, swz ^(r&7)
    unsigned short* Pl = (unsigned short*)(smem + 65536);  // [4][32*64] per-wave P, swz ^(row&7)

    const int t = threadIdx.x;
    const int wave = t >> 6, lane = t & 63, quad = lane >> 4, l15 = lane & 15;
    const int bh = blockIdx.x;
    const int yq = blockIdx.y;
    const int qt = (yq < 4) ? yq : (11 - yq);
    const int b = bh >> 4, h = bh & 15;

    bf16x8 qf[2][4];
    #pragma unroll
    for (int rt = 0; rt < 2; rt++) {
        const size_t qoff = (size_t)(b*1024 + qt*128 + wave*32 + rt*16 + l15) * 2048 + h*128;
        #pragma unroll
        for (int ks = 0; ks < 4; ks++)
            qf[rt][ks] = __builtin_bit_cast(bf16x8, *(const uint4*)(q_buf + qoff + ks*32 + quad*8));
    }

    f32x4 ctx[2][8];
    #pragma unroll
    for (int rt = 0; rt < 2; rt++)
        #pragma unroll
        for (int i = 0; i < 8; i++) ctx[rt][i] = zero4();
    float l_run[2][4];
    #pragma unroll
    for (int rt = 0; rt < 2; rt++)
        #pragma unroll
        for (int r = 0; r < 4; r++) l_run[rt][r] = 0.f;

    const size_t kbase = (size_t)b * 1024 * 2048 + h*128;
    const size_t vbase = (size_t)(b*16 + h) * 131072;
    const int row0 = qt*128 + wave*32;
    const int kiters = 2*qt + 2;

    unsigned short* Plw = Pl + wave*2048;

    // prologue: stage tile 0 into buf 0
    {
        #pragma unroll
        for (int p = 0; p < 4; p++) {
            int c = p*4 + wave;
            {   int s = c*64 + lane;
                int r = s >> 4;
                int g = (s & 15) ^ (r & 15);
                gl_lds16(k_buf + kbase + (size_t)(0*64 + r) * 2048 + g*8, Ks + c*64);
            }
            {   int s = c*64 + lane;
                int r = s >> 3;
                int g = (lane & 7) ^ (r & 7);
                gl_lds16(vt_buf + vbase + (size_t)r * 1024 + 0*64 + g*8, Vs + c*64);
            }
        }
    }
    __syncthreads();   // drains vmcnt(0): tile 0 resident

    for (int kt = 0; kt < kiters; kt++) {
        const int d = kt & 1;

        // issue next tile's stage into the other buffer (latency hidden under compute)
        if (kt + 1 < kiters) {
            const int dn = d ^ 1;
            #pragma unroll
            for (int p = 0; p < 4; p++) {
                int c = p*4 + wave;
                {   int s = c*64 + lane;
                    int r = s >> 4;
                    int g = (s & 15) ^ (r & 15);
                    gl_lds16(k_buf + kbase + (size_t)((kt+1)*64 + r) * 2048 + g*8,
                             Ks + dn*1024 + c*64);
                }
                {   int s = c*64 + lane;
                    int r = s >> 3;
                    int g = (lane & 7) ^ (r & 7);
                    gl_lds16(vt_buf + vbase + (size_t)r * 1024 + (kt+1)*64 + g*8,
                             Vs + dn*1024 + c*64);
                }
            }
        }

        if (kt*64 <= row0 + 31) {                 // wave has live rows this tile
            const bool needmask = (kt*64 + 63 > row0);
            const uint4* Kd = Ks + d*1024;
            const uint4* Vd = Vs + d*1024;

            // S = Q K^T, K-fragment shared across both row-tiles
            f32x4 sacc[2][4];
            #pragma unroll
            for (int rt = 0; rt < 2; rt++)
                #pragma unroll
                for (int nt = 0; nt < 4; nt++) sacc[rt][nt] = zero4();
            #pragma unroll
            for (int ks = 0; ks < 4; ks++)
                #pragma unroll
                for (int nt = 0; nt < 4; nt++) {
                    int key = nt*16 + l15;
                    int g = (ks*4 + quad) ^ (key & 15);
                    bf16x8 kf = __builtin_bit_cast(bf16x8, Kd[key*16 + g]);
                    sacc[0][nt] = __builtin_amdgcn_mfma_f32_16x16x32_bf16(qf[0][ks], kf, sacc[0][nt], 0, 0, 0);
                    sacc[1][nt] = __builtin_amdgcn_mfma_f32_16x16x32_bf16(qf[1][ks], kf, sacc[1][nt], 0, 0, 0);
                }

            #pragma unroll
            for (int rt = 0; rt < 2; rt++) {
                float pv[4][4];
                if (needmask) {
                    #pragma unroll
                    for (int nt = 0; nt < 4; nt++)
                        #pragma unroll
                        for (int r = 0; r < 4; r++) {
                            bool masked = (kt*64 + nt*16 + l15 > row0 + rt*16 + quad*4 + r);
                            pv[nt][r] = masked ? 0.f : __expf(sacc[rt][nt][r]);
                        }
                } else {
                    #pragma unroll
                    for (int nt = 0; nt < 4; nt++)
                        #pragma unroll
                        for (int r = 0; r < 4; r++)
                            pv[nt][r] = __expf(sacc[rt][nt][r]);
                }
                #pragma unroll
                for (int r = 0; r < 4; r++)
                    l_run[rt][r] += (pv[0][r] + pv[1][r]) + (pv[2][r] + pv[3][r]);

                #pragma unroll
                for (int nt = 0; nt < 4; nt++)
                    #pragma unroll
                    for (int r = 0; r < 4; r++) {
                        int row = rt*16 + quad*4 + r;
                        int col = nt*16 + l15;
                        int gc = (col >> 3) ^ (row & 7);
                        Plw[row*64 + gc*8 + (col & 7)] = f2bf(pv[nt][r]);
                    }
            }
            __asm__ volatile("s_waitcnt lgkmcnt(0)" ::: "memory");

            // ctx += P V, V-fragment shared across both row-tiles
            #pragma unroll
            for (int ks = 0; ks < 2; ks++) {
                bf16x8 pa[2];
                #pragma unroll
                for (int rt = 0; rt < 2; rt++) {
                    int row = rt*16 + l15;
                    int gp = (ks*4 + quad) ^ (row & 7);
                    pa[rt] = __builtin_bit_cast(bf16x8, *(const uint4*)&Plw[row*64 + gp*8]);
                }
                #pragma unroll
                for (int dt = 0; dt < 8; dt++) {
                    int drow = dt*16 + l15;
                    int gv = (ks*4 + quad) ^ (drow & 7);
                    bf16x8 vf = __builtin_bit_cast(bf16x8, Vd[drow*8 + gv]);
                    ctx[0][dt] = __builtin_amdgcn_mfma_f32_16x16x32_bf16(pa[0], vf, ctx[0][dt], 0, 0, 0);
                    ctx[1][dt] = __builtin_amdgcn_mfma_f32_16x16x32_bf16(pa[1], vf, ctx[1][dt], 0, 0, 0);
                }
            }
        }

        // one barrier per iter: drains our stage(t+1) loads (covered by compute above) and
        // guarantees all waves are done reading buffer d before iter t+1 restages it (t+2 -> d).
        __syncthreads();
    }

    // finalize
    #pragma unroll
    for (int rt = 0; rt < 2; rt++) {
        float inv[4];
        #pragma unroll
        for (int r = 0; r < 4; r++) {
            float l = l_run[rt][r];
            l += __shfl_xor(l, 1);
            l += __shfl_xor(l, 2);
            l += __shfl_xor(l, 4);
            l += __shfl_xor(l, 8);
            inv[r] = 1.0f / l;
        }
        const int tt0 = b*1024 + qt*128 + wave*32 + rt*16 + quad*4;
        #pragma unroll
        for (int dt = 0; dt < 8; dt++)
            #pragma unroll
            for (int r = 0; r < 4; r++)
                ctx_buf[(size_t)(tt0 + r) * 2048 + h*128 + dt*16 + l15] = f2bf(ctx[rt][dt][r] * inv[r]);
    }
}

// ---------------- launch ----------------
extern "C" void kernel_launch(void* const* d_in, const int* in_sizes, int n_in,
                              void* d_out, int out_size, void* d_ws, size_t ws_size,
                              hipStream_t stream) {
    const float* hs    = (const float*)d_in[0];
    const float* wqkv  = (const float*)d_in[1];
    const float* bqkv  = (const float*)d_in[2];
    const float* wproj = (const float*)d_in[3];
    const float* bproj = (const float*)d_in[4];

    char* ws = (char*)d_ws;
    unsigned short* hs_bf   = (unsigned short*)(ws);
    unsigned short* wqkvT   = (unsigned short*)(ws + 16777216ull);
    unsigned short* wprojT  = (unsigned short*)(ws + 41943040ull);
    unsigned short* q_buf   = (unsigned short*)(ws + 50331648ull);
    unsigned short* k_buf   = (unsigned short*)(ws + 67108864ull);
    unsigned short* vt_buf  = (unsigned short*)(ws + 83886080ull);
    unsigned short* ctx_buf = (unsigned short*)(ws + 100663296ull);

    static bool attr_set = false;
    if (!attr_set) {
        (void)hipFuncSetAttribute((const void*)k_attn,
                                  hipFuncAttributeMaxDynamicSharedMemorySize, 81920);
        attr_set = true;
    }

    k_prep<<<18432, 256, 0, stream>>>(hs, hs_bf, wqkv, wqkvT, wproj, wprojT);
    k_gemm_qkv<<<dim3(32, 48), 256, 0, stream>>>(hs_bf, wqkvT, bqkv, q_buf, k_buf, vt_buf, 2048);
    k_attn<<<dim3(64, 8), 256, 81920, stream>>>(q_buf, k_buf, vt_buf, ctx_buf);
    k_gemm_proj<<<dim3(64, 16), 256, 0, stream>>>(ctx_buf, wprojT, bproj, (float*)d_out, 2048, 2048);
}